// Round 6
// baseline (548.161 us; speedup 1.0000x reference)
//
#include <hip/hip_runtime.h>

#define HSZ  32
#define TLEN 1024
#define CS   36   // u32 stride per col in an h plane (144 B: 16B-aligned, even spread)

typedef _Float16 half8 __attribute__((ext_vector_type(8)));
typedef float    f32x4 __attribute__((ext_vector_type(4)));

__device__ __forceinline__ float rcp_f(float x){ return __builtin_amdgcn_rcpf(x); }
__device__ __forceinline__ float exp2_f(float x){ return __builtin_amdgcn_exp2f(x); }
#define LOG2E 1.442695040888963f
__device__ __forceinline__ float sigmoid_f(float x){ return rcp_f(1.0f + exp2_f(-LOG2E*x)); }
__device__ __forceinline__ float tanh_fast(float x){ return 1.0f - 2.0f*rcp_f(1.0f + exp2_f(2.0f*LOG2E*x)); }
__device__ __forceinline__ f32x4 mfma16(half8 a, half8 b, f32x4 c){
  return __builtin_amdgcn_mfma_f32_16x16x32_f16(a, b, c, 0, 0, 0);
}

// LDS-only barrier: drain lgkmcnt (ds_writes visible) WITHOUT draining vmcnt,
// so the x global prefetch stays in flight across step barriers.
__device__ __forceinline__ void lds_barrier(){
  asm volatile("s_waitcnt lgkmcnt(0)\n\ts_barrier" ::: "memory");
}

// Split a f32 into (hi,lo) f16 pair packed in one u32 (hi in low 16 bits).
__device__ __forceinline__ unsigned int packsplit(float v){
  _Float16 hi = (_Float16)v;
  _Float16 lo = (_Float16)(v - (float)hi);
  unsigned short a = __builtin_bit_cast(unsigned short, hi);
  unsigned short b = __builtin_bit_cast(unsigned short, lo);
  return (unsigned int)a | ((unsigned int)b << 16);
}

// 8 waves = one 16-batch tile; wave w owns states 4w..4w+3 (permuted A-row trick:
// lane (g,col) D-regs j=0..3 are gates (i,f,g,o) of state s=4w+g: quad in-lane).
// EXACT interleaved split: h as u32 (f16 hi, f16 lo); MFMA pairs (I + S frags)
// give sum_k (wh+wl)(hh+hl) exactly.
//
// SOFTWARE-PIPELINED LAYERS: after the exchange publishing h0(t), both L1(t)
// (h0(t), h1(t-1)) and L0(t+1) (h0(t), x(t+1)) are computable. Each iteration
// runs them as parallel chains: 3 independent MFMA chains + 2 independent
// activation chains, then writes h1(t), h0(t+1), ONE lgkm barrier, reads both.
// Critical path per step drops from L0+L1 serial to max(L0, L1).
__global__ __launch_bounds__(512, 2) void lstm2_mfma6(
    const float* __restrict__ x,
    const float* __restrict__ Wih0, const float* __restrict__ Whh0,
    const float* __restrict__ bih0, const float* __restrict__ bhh0,
    const float* __restrict__ Wih1, const float* __restrict__ Whh1,
    const float* __restrict__ bih1, const float* __restrict__ bhh1,
    const float* __restrict__ Wfc,  const float* __restrict__ bfc,
    float* __restrict__ out, int Tn)
{
  __shared__ __align__(16) unsigned int hw[2][2][16*CS];  // [parity][layer][col*CS + k]

  const int tid = threadIdx.x;
  const int w   = tid >> 6;
  const int l   = tid & 63;
  const int col = l & 15;        // batch col == A tile-row index
  const int g   = l >> 4;        // k-group == D row-group
  const int s   = 4*w + g;       // state this lane owns
  const int b0  = blockIdx.x * 16;

  // ---- A fragments (interleaved + swapped), permuted rows ----
  const int prow = 32*(col & 3) + 4*w + (col >> 2);
  half8 A0I0, A0I1, A0S0, A0S1;   // Whh0
  half8 AII0, AII1, AIS0, AIS1;   // Wih1
  half8 AHI0, AHI1, AHS0, AHS1;   // Whh1
  {
    const float* rows[3] = { Whh0 + prow*HSZ, Wih1 + prow*HSZ, Whh1 + prow*HSZ };
    half8* I0[3] = { &A0I0, &AII0, &AHI0 };
    half8* I1[3] = { &A0I1, &AII1, &AHI1 };
    half8* S0[3] = { &A0S0, &AIS0, &AHS0 };
    half8* S1[3] = { &A0S1, &AIS1, &AHS1 };
    #pragma unroll
    for (int m3 = 0; m3 < 3; ++m3){
      #pragma unroll
      for (int H = 0; H < 2; ++H){
        half8& I = H ? *I1[m3] : *I0[m3];
        half8& S = H ? *S1[m3] : *S0[m3];
        #pragma unroll
        for (int m = 0; m < 4; ++m){
          float v = rows[m3][16*H + 4*g + m];
          _Float16 hi = (_Float16)v;
          _Float16 lo = (_Float16)(v - (float)hi);
          I[2*m] = hi; I[2*m+1] = lo;
          S[2*m] = lo; S[2*m+1] = hi;
        }
      }
    }
  }
  // D reg j = physical gate row 32j + s
  float wx[4], bs0[4];
  f32x4 bias1;
  #pragma unroll
  for (int j = 0; j < 4; ++j){
    int r   = 32*j + s;
    wx[j]   = Wih0[r];
    bs0[j]  = bih0[r] + bhh0[r];
    bias1[j]= bih1[r] + bhh1[r];
  }

  const int wrI = col*CS + s;        // u32 index for this lane's h write
  const int rdI = col*CS + 4*g;      // u32 index of b128 read (half 0); +16 for half 1

  for (int i = tid; i < 2*2*16*CS; i += 512) (&hw[0][0][0])[i] = 0u;
  __syncthreads();

  const float* xp = x + (size_t)(b0 + col) * Tn;
  float c0, c1 = 0.f, h1v = 0.f;

  // ---- prologue: L0(0) has h0(-1)=0 -> no MFMA ----
  {
    float x0 = xp[0];
    float e0 = fmaf(x0, wx[0], bs0[0]);
    float e1 = fmaf(x0, wx[1], bs0[1]);
    float e2 = fmaf(x0, wx[2], bs0[2]);
    float e3 = fmaf(x0, wx[3], bs0[3]);
    float i0 = sigmoid_f(e0);
    float g0 = tanh_fast(e2);
    float o0 = sigmoid_f(e3);
    (void)e1;
    c0 = i0 * g0;                       // f0 * c0(-1) = 0
    float h0 = o0 * tanh_fast(c0);
    hw[0][0][wrI] = packsplit(h0);      // h1(-1) stays 0 in hw[0][1]
  }
  __syncthreads();
  half8 B00 = *(const half8*)&hw[0][0][rdI];        // h0(0)
  half8 B01 = *(const half8*)&hw[0][0][rdI + 16];
  half8 B10 = *(const half8*)&hw[0][1][rdI];        // h1(-1) = 0
  half8 B11 = *(const half8*)&hw[0][1][rdI + 16];
  float xv = xp[1];                                  // x(1), consumed in iter 0

  // iter t: computes L1(t) -> h1(t)  AND  L0(t+1) -> h0(t+1); parity Q=(t+1)&1
#define STEP(Q, TIDX)                                                      \
  {                                                                        \
    float xn = xp[(TIDX)];              /* prefetch x(t+2), in flight */   \
    f32x4 e, u, v2 = {0.f, 0.f, 0.f, 0.f};                                 \
    e[0] = fmaf(xv, wx[0], bs0[0]);                                        \
    e[1] = fmaf(xv, wx[1], bs0[1]);                                        \
    e[2] = fmaf(xv, wx[2], bs0[2]);                                        \
    e[3] = fmaf(xv, wx[3], bs0[3]);                                        \
    u = bias1;                                                             \
    __builtin_amdgcn_s_setprio(1);                                         \
    e  = mfma16(A0I0, B00, e);  u  = mfma16(AHI0, B10, u);                 \
    v2 = mfma16(AHI1, B11, v2); e  = mfma16(A0S0, B00, e);                 \
    u  = mfma16(AHS0, B10, u);  v2 = mfma16(AHS1, B11, v2);                \
    e  = mfma16(A0I1, B01, e);  u  = mfma16(AII0, B00, u);                 \
    v2 = mfma16(AII1, B01, v2); e  = mfma16(A0S1, B01, e);                 \
    u  = mfma16(AIS0, B00, u);  v2 = mfma16(AIS1, B01, v2);                \
    __builtin_amdgcn_s_setprio(0);                                         \
    /* L1(t) activations */                                                \
    float i1 = sigmoid_f(u[0] + v2[0]), f1 = sigmoid_f(u[1] + v2[1]);      \
    float g1 = tanh_fast(u[2] + v2[2]), o1 = sigmoid_f(u[3] + v2[3]);      \
    c1 = fmaf(f1, c1, i1 * g1);                                            \
    h1v = o1 * tanh_fast(c1);                                              \
    hw[(Q)][1][wrI] = packsplit(h1v);                                      \
    /* L0(t+1) activations */                                              \
    float i0 = sigmoid_f(e[0]), f0 = sigmoid_f(e[1]);                      \
    float g0 = tanh_fast(e[2]), o0 = sigmoid_f(e[3]);                      \
    c0 = fmaf(f0, c0, i0 * g0);                                            \
    float h0 = o0 * tanh_fast(c0);                                         \
    hw[(Q)][0][wrI] = packsplit(h0);                                       \
    lds_barrier();                                                         \
    B00 = *(const half8*)&hw[(Q)][0][rdI];                                 \
    B01 = *(const half8*)&hw[(Q)][0][rdI + 16];                            \
    B10 = *(const half8*)&hw[(Q)][1][rdI];                                 \
    B11 = *(const half8*)&hw[(Q)][1][rdI + 16];                            \
    xv = xn;                                                               \
  }

  for (int T0 = 0; T0 < Tn; T0 += 4){
    STEP(1, T0 + 2);
    STEP(0, T0 + 3);
    STEP(1, (T0 + 4 < Tn) ? T0 + 4 : Tn - 1);
    STEP(0, (T0 + 5 < Tn) ? T0 + 5 : Tn - 1);
  }
#undef STEP

  // ---- FC head: out[b0+c] = dot(h1_final[:,c], Wfc) + bfc ----
  __syncthreads();
  float* sc = (float*)&hw[0][0][0];
  sc[s*17 + col] = h1v;
  __syncthreads();
  if (tid < 16){
    float acc = bfc[0];
    #pragma unroll 8
    for (int k = 0; k < HSZ; ++k) acc = fmaf(sc[k*17 + tid], Wfc[k], acc);
    out[b0 + tid] = acc;
  }
}

extern "C" void kernel_launch(void* const* d_in, const int* in_sizes, int n_in,
                              void* d_out, int out_size, void* d_ws, size_t ws_size,
                              hipStream_t stream) {
  const float* x    = (const float*)d_in[0];
  const float* Wih0 = (const float*)d_in[1];
  const float* Whh0 = (const float*)d_in[2];
  const float* bih0 = (const float*)d_in[3];
  const float* bhh0 = (const float*)d_in[4];
  const float* Wih1 = (const float*)d_in[5];
  const float* Whh1 = (const float*)d_in[6];
  const float* bih1 = (const float*)d_in[7];
  const float* bhh1 = (const float*)d_in[8];
  const float* Wfc  = (const float*)d_in[9];
  const float* bfc  = (const float*)d_in[10];
  float* out = (float*)d_out;

  const int Tn = TLEN;
  const int B  = in_sizes[0] / Tn;     // x is (B, T, 1)

  dim3 block(512);
  dim3 grid(B / 16);
  hipLaunchKernelGGL(lstm2_mfma6, grid, block, 0, stream,
                     x, Wih0, Whh0, bih0, bhh0, Wih1, Whh1, bih1, bhh1,
                     Wfc, bfc, out, Tn);
}

// Round 7
// 499.515 us; speedup vs baseline: 1.0974x; 1.0974x over previous
//
#include <hip/hip_runtime.h>

#define HSZ  32
#define TLEN 1024
#define PS   40   // f16 stride per col in a plane (80 B: 16B-aligned b128 reads)

typedef _Float16 half8 __attribute__((ext_vector_type(8)));
typedef float    f32x4 __attribute__((ext_vector_type(4)));

__device__ __forceinline__ float rcp_f(float x){ return __builtin_amdgcn_rcpf(x); }
__device__ __forceinline__ float exp2_f(float x){ return __builtin_amdgcn_exp2f(x); }
#define LOG2E 1.442695040888963f
__device__ __forceinline__ float sigmoid_f(float x){ return rcp_f(1.0f + exp2_f(-LOG2E*x)); }
__device__ __forceinline__ float tanh_fast(float x){ return 1.0f - 2.0f*rcp_f(1.0f + exp2_f(2.0f*LOG2E*x)); }
__device__ __forceinline__ f32x4 mfma16(half8 a, half8 b, f32x4 c){
  return __builtin_amdgcn_mfma_f32_16x16x32_f16(a, b, c, 0, 0, 0);
}

// LDS-only barrier: drain lgkmcnt (ds ops visible) WITHOUT draining vmcnt,
// so the x global prefetch stays in flight across step barriers.
__device__ __forceinline__ void lds_barrier(){
  asm volatile("s_waitcnt lgkmcnt(0)\n\ts_barrier" ::: "memory");
}

// 8 waves = one 16-batch tile; permuted A-row trick: A tile-row r loads physical
// gate row 32*(r&3)+4w+(r>>2), so lane (g,col) D-regs j=0..3 are gates (i,f,g,o)
// of state s=4w+g -- whole quad in-lane, no gate LDS round-trip.
//
// SEPARATE-PLANE SPLIT (9 MFMA/step): h stored as hi-plane + lo-plane (f16).
// Each MFMA covers the full k=32, so a matvec = Wh*Hh + Wh*Hl + Wl*Hh
// (3 MFMA; dropped Wl*Hl term is ~2^-22 -- R3-validated exact enough).
// Three independent depth-3 chains: e (L0), u (Whh1*h1, seeded by bias1 via
// C-operand), v (Wih1*h0, seeded by loop-invariant zero4). No accumulator movs.
// Skewed schedule: iteration t computes L1(t) and L0(t+1) in one region;
// ONE lgkm-only barrier per step; parity double-buffered planes.
__global__ __launch_bounds__(512, 2) void lstm2_mfma7(
    const float* __restrict__ x,
    const float* __restrict__ Wih0, const float* __restrict__ Whh0,
    const float* __restrict__ bih0, const float* __restrict__ bhh0,
    const float* __restrict__ Wih1, const float* __restrict__ Whh1,
    const float* __restrict__ bih1, const float* __restrict__ bhh1,
    const float* __restrict__ Wfc,  const float* __restrict__ bfc,
    float* __restrict__ out, int Tn)
{
  // [parity][layer][hi/lo][col*PS + k]
  __shared__ __align__(16) _Float16 hpl[2][2][2][16*PS];

  const int tid = threadIdx.x;
  const int w   = tid >> 6;
  const int l   = tid & 63;
  const int col = l & 15;        // batch col == A tile-row index
  const int g   = l >> 4;        // k-group == D row-group
  const int s   = 4*w + g;       // state this lane owns
  const int b0  = blockIdx.x * 16;

  // ---- A fragments: hi + lo halves, permuted rows, k = 8g+j ----
  const int prow = 32*(col & 3) + 4*w + (col >> 2);
  half8 W0h, W0l, WIh, WIl, WHh, WHl;
  {
    const float* p0 = Whh0 + prow*HSZ + 8*g;
    const float* p1 = Wih1 + prow*HSZ + 8*g;
    const float* p2 = Whh1 + prow*HSZ + 8*g;
    #pragma unroll
    for (int j = 0; j < 8; ++j){
      float v0 = p0[j], v1 = p1[j], v2 = p2[j];
      _Float16 a = (_Float16)v0; W0h[j] = a; W0l[j] = (_Float16)(v0 - (float)a);
      _Float16 b = (_Float16)v1; WIh[j] = b; WIl[j] = (_Float16)(v1 - (float)b);
      _Float16 c = (_Float16)v2; WHh[j] = c; WHl[j] = (_Float16)(v2 - (float)c);
    }
  }
  // D reg j = physical gate row 32j + s
  float wx[4], bs0[4];
  f32x4 bias1;
  #pragma unroll
  for (int j = 0; j < 4; ++j){
    int r    = 32*j + s;
    wx[j]    = Wih0[r];
    bs0[j]   = bih0[r] + bhh0[r];
    bias1[j] = bih1[r] + bhh1[r];
  }
  const f32x4 zero4 = {0.f, 0.f, 0.f, 0.f};   // loop-invariant C-seed (C != D: no copies)

  const int wrI = col*PS + s;        // f16 index of this lane's h write
  const int rdI = col*PS + 8*g;      // f16 index of b128 read (16B-aligned)

  for (int i = tid; i < 2*2*2*16*PS; i += 512) (&hpl[0][0][0][0])[i] = (_Float16)0.0f;

  const float* xp = x + (size_t)(b0 + col) * Tn;
  float c0, c1 = 0.f, h1v = 0.f;

  // ---- prologue: L0(0) has h0(-1)=0 -> no MFMA; h1(-1)=0 stays in [0][1] ----
  {
    float x0 = xp[0];
    float e0 = fmaf(x0, wx[0], bs0[0]);
    float e2 = fmaf(x0, wx[2], bs0[2]);
    float e3 = fmaf(x0, wx[3], bs0[3]);
    float i0 = sigmoid_f(e0);
    float g0 = tanh_fast(e2);
    float o0 = sigmoid_f(e3);
    c0 = i0 * g0;                       // f0 * c0(-1) = 0
    float h0 = o0 * tanh_fast(c0);
    __syncthreads();                    // zero-init visible before overwrite/read
    _Float16 hh = (_Float16)h0;
    hpl[0][0][0][wrI] = hh;
    hpl[0][0][1][wrI] = (_Float16)(h0 - (float)hh);
  }
  __syncthreads();
  half8 Bh0h = *(const half8*)&hpl[0][0][0][rdI];   // h0(0) hi
  half8 Bh0l = *(const half8*)&hpl[0][0][1][rdI];   // h0(0) lo
  half8 Bh1h = *(const half8*)&hpl[0][1][0][rdI];   // h1(-1) = 0
  half8 Bh1l = *(const half8*)&hpl[0][1][1][rdI];
  float xv = xp[1];                                  // x(1), consumed in iter 0

  // iter t: computes L1(t) -> h1(t)  AND  L0(t+1) -> h0(t+1); Q=(t+1)&1
#define STEP(Q, TIDX)                                                      \
  {                                                                        \
    float xn = xp[(TIDX)];              /* prefetch x(t+2), stays in flight */ \
    f32x4 e;                                                               \
    e[0] = fmaf(xv, wx[0], bs0[0]);                                        \
    e[1] = fmaf(xv, wx[1], bs0[1]);                                        \
    e[2] = fmaf(xv, wx[2], bs0[2]);                                        \
    e[3] = fmaf(xv, wx[3], bs0[3]);                                        \
    f32x4 u, vv;                                                           \
    __builtin_amdgcn_s_setprio(1);                                         \
    e = mfma16(W0h, Bh0h, e);  u = mfma16(WHh, Bh1h, bias1);               \
    vv = mfma16(WIh, Bh0h, zero4);                                         \
    e = mfma16(W0h, Bh0l, e);  u = mfma16(WHh, Bh1l, u);                   \
    vv = mfma16(WIh, Bh0l, vv);                                            \
    e = mfma16(W0l, Bh0h, e);  u = mfma16(WHl, Bh1h, u);                   \
    vv = mfma16(WIl, Bh0h, vv);                                            \
    __builtin_amdgcn_s_setprio(0);                                         \
    /* L1(t) */                                                            \
    float i1 = sigmoid_f(u[0] + vv[0]), f1 = sigmoid_f(u[1] + vv[1]);      \
    float g1 = tanh_fast(u[2] + vv[2]), o1 = sigmoid_f(u[3] + vv[3]);      \
    c1 = fmaf(f1, c1, i1 * g1);                                            \
    h1v = o1 * tanh_fast(c1);                                              \
    _Float16 h1h = (_Float16)h1v;                                          \
    hpl[(Q)][1][0][wrI] = h1h;                                             \
    hpl[(Q)][1][1][wrI] = (_Float16)(h1v - (float)h1h);                    \
    /* L0(t+1) */                                                          \
    float i0 = sigmoid_f(e[0]), f0 = sigmoid_f(e[1]);                      \
    float g0 = tanh_fast(e[2]), o0 = sigmoid_f(e[3]);                      \
    c0 = fmaf(f0, c0, i0 * g0);                                            \
    float h0 = o0 * tanh_fast(c0);                                         \
    _Float16 h0h = (_Float16)h0;                                           \
    hpl[(Q)][0][0][wrI] = h0h;                                             \
    hpl[(Q)][0][1][wrI] = (_Float16)(h0 - (float)h0h);                     \
    lds_barrier();                                                         \
    Bh0h = *(const half8*)&hpl[(Q)][0][0][rdI];                            \
    Bh0l = *(const half8*)&hpl[(Q)][0][1][rdI];                            \
    Bh1h = *(const half8*)&hpl[(Q)][1][0][rdI];                            \
    Bh1l = *(const half8*)&hpl[(Q)][1][1][rdI];                            \
    xv = xn;                                                               \
  }

  for (int T0 = 0; T0 < Tn; T0 += 4){
    STEP(1, T0 + 2);
    STEP(0, T0 + 3);
    STEP(1, (T0 + 4 < Tn) ? T0 + 4 : Tn - 1);
    STEP(0, (T0 + 5 < Tn) ? T0 + 5 : Tn - 1);
  }
#undef STEP

  // ---- FC head: out[b0+c] = dot(h1_final[:,c], Wfc) + bfc ----
  __syncthreads();
  float* sc = (float*)&hpl[0][0][0][0];
  sc[s*17 + col] = h1v;
  __syncthreads();
  if (tid < 16){
    float acc = bfc[0];
    #pragma unroll 8
    for (int k = 0; k < HSZ; ++k) acc = fmaf(sc[k*17 + tid], Wfc[k], acc);
    out[b0 + tid] = acc;
  }
}

extern "C" void kernel_launch(void* const* d_in, const int* in_sizes, int n_in,
                              void* d_out, int out_size, void* d_ws, size_t ws_size,
                              hipStream_t stream) {
  const float* x    = (const float*)d_in[0];
  const float* Wih0 = (const float*)d_in[1];
  const float* Whh0 = (const float*)d_in[2];
  const float* bih0 = (const float*)d_in[3];
  const float* bhh0 = (const float*)d_in[4];
  const float* Wih1 = (const float*)d_in[5];
  const float* Whh1 = (const float*)d_in[6];
  const float* bih1 = (const float*)d_in[7];
  const float* bhh1 = (const float*)d_in[8];
  const float* Wfc  = (const float*)d_in[9];
  const float* bfc  = (const float*)d_in[10];
  float* out = (float*)d_out;

  const int Tn = TLEN;
  const int B  = in_sizes[0] / Tn;     // x is (B, T, 1)

  dim3 block(512);
  dim3 grid(B / 16);
  hipLaunchKernelGGL(lstm2_mfma7, grid, block, 0, stream,
                     x, Wih0, Whh0, bih0, bhh0, Wih1, Whh1, bih1, bhh1,
                     Wfc, bfc, out, Tn);
}

// Round 8
// 427.021 us; speedup vs baseline: 1.2837x; 1.1698x over previous
//
#include <hip/hip_runtime.h>

#define HSZ  32
#define TLEN 1024
#define PS   40   // f16 stride per col in a plane (80 B: 16B-aligned b128 reads)

typedef _Float16 half8 __attribute__((ext_vector_type(8)));
typedef float    f32x4 __attribute__((ext_vector_type(4)));

__device__ __forceinline__ float rcp_f(float x){ return __builtin_amdgcn_rcpf(x); }
__device__ __forceinline__ float exp2_f(float x){ return __builtin_amdgcn_exp2f(x); }
#define LOG2E 1.442695040888963f
__device__ __forceinline__ float sigmoid_f(float x){ return rcp_f(1.0f + exp2_f(-LOG2E*x)); }
__device__ __forceinline__ float tanh_fast(float x){ return 1.0f - 2.0f*rcp_f(1.0f + exp2_f(2.0f*LOG2E*x)); }
__device__ __forceinline__ f32x4 mfma16(half8 a, half8 b, f32x4 c){
  return __builtin_amdgcn_mfma_f32_16x16x32_f16(a, b, c, 0, 0, 0);
}

// LDS-only barrier: drain lgkmcnt (ds ops visible) WITHOUT draining vmcnt,
// so the x global prefetch stays in flight across step barriers.
__device__ __forceinline__ void lds_barrier(){
  asm volatile("s_waitcnt lgkmcnt(0)\n\ts_barrier" ::: "memory");
}

// 8 waves = one 16-batch tile; permuted A-row trick: A tile-row r loads physical
// gate row 32*(r&3)+4w+(r>>2), so lane (g,col) D-regs j=0..3 are gates (i,f,g,o)
// of state s=4w+g -- whole quad in-lane, no gate LDS round-trip.
//
// h EXCHANGED AS f16-HI ONLY (lo-plane dropped): h rounding is random per step
// and contracted by the forget gate -- rms output error ~1e-5, 16x under the
// 8.3e-4 threshold. Weights KEEP their hi+lo split (systematic error otherwise).
// matvec = Wh*H + Wl*H -> 6 MFMA/step in three depth-2 chains:
//   e  (L0):  W0h*Bh0 -> W0l*Bh0   (seeded by x*wx + bias FMAs)
//   u  (L1):  WHh*Bh1 -> WHl*Bh1   (seeded by bias1 via C operand)
//   vv (L1):  WIh*Bh0 -> WIl*Bh0   (seeded by loop-invariant zero4)
// Skewed schedule: iter t computes L1(t) and L0(t+1); ONE lgkm-only barrier;
// parity double-buffered planes; 2 ds_read_b128 + 2 ds_write_b16 per step.
__global__ __launch_bounds__(512, 2) void lstm2_mfma8(
    const float* __restrict__ x,
    const float* __restrict__ Wih0, const float* __restrict__ Whh0,
    const float* __restrict__ bih0, const float* __restrict__ bhh0,
    const float* __restrict__ Wih1, const float* __restrict__ Whh1,
    const float* __restrict__ bih1, const float* __restrict__ bhh1,
    const float* __restrict__ Wfc,  const float* __restrict__ bfc,
    float* __restrict__ out, int Tn)
{
  // [parity][layer][col*PS + k]  (f16 hi plane only)
  __shared__ __align__(16) _Float16 hpl[2][2][16*PS];

  const int tid = threadIdx.x;
  const int w   = tid >> 6;
  const int l   = tid & 63;
  const int col = l & 15;        // batch col == A tile-row index
  const int g   = l >> 4;        // k-group == D row-group
  const int s   = 4*w + g;       // state this lane owns
  const int b0  = blockIdx.x * 16;

  // ---- A fragments: hi + lo halves, permuted rows, k = 8g+j ----
  const int prow = 32*(col & 3) + 4*w + (col >> 2);
  half8 W0h, W0l, WIh, WIl, WHh, WHl;
  {
    const float* p0 = Whh0 + prow*HSZ + 8*g;
    const float* p1 = Wih1 + prow*HSZ + 8*g;
    const float* p2 = Whh1 + prow*HSZ + 8*g;
    #pragma unroll
    for (int j = 0; j < 8; ++j){
      float v0 = p0[j], v1 = p1[j], v2 = p2[j];
      _Float16 a = (_Float16)v0; W0h[j] = a; W0l[j] = (_Float16)(v0 - (float)a);
      _Float16 b = (_Float16)v1; WIh[j] = b; WIl[j] = (_Float16)(v1 - (float)b);
      _Float16 c = (_Float16)v2; WHh[j] = c; WHl[j] = (_Float16)(v2 - (float)c);
    }
  }
  // D reg j = physical gate row 32j + s
  float wx[4], bs0[4];
  f32x4 bias1;
  #pragma unroll
  for (int j = 0; j < 4; ++j){
    int r    = 32*j + s;
    wx[j]    = Wih0[r];
    bs0[j]   = bih0[r] + bhh0[r];
    bias1[j] = bih1[r] + bhh1[r];
  }
  const f32x4 zero4 = {0.f, 0.f, 0.f, 0.f};   // loop-invariant C-seed (C != D)

  const int wrI = col*PS + s;        // f16 index of this lane's h write
  const int rdI = col*PS + 8*g;      // f16 index of b128 read (16B-aligned)

  for (int i = tid; i < 2*2*16*PS; i += 512) (&hpl[0][0][0])[i] = (_Float16)0.0f;

  const float* xp = x + (size_t)(b0 + col) * Tn;
  float c0, c1 = 0.f, h1v = 0.f;

  // ---- prologue: L0(0) has h0(-1)=0 -> no MFMA; h1(-1)=0 stays in [0][1] ----
  {
    float x0 = xp[0];
    float e0 = fmaf(x0, wx[0], bs0[0]);
    float e2 = fmaf(x0, wx[2], bs0[2]);
    float e3 = fmaf(x0, wx[3], bs0[3]);
    float i0 = sigmoid_f(e0);
    float g0 = tanh_fast(e2);
    float o0 = sigmoid_f(e3);
    c0 = i0 * g0;                       // f0 * c0(-1) = 0
    float h0 = o0 * tanh_fast(c0);
    __syncthreads();                    // zero-init visible before overwrite/read
    hpl[0][0][wrI] = (_Float16)h0;
  }
  __syncthreads();
  half8 Bh0 = *(const half8*)&hpl[0][0][rdI];   // h0(0)
  half8 Bh1 = *(const half8*)&hpl[0][1][rdI];   // h1(-1) = 0
  float xv = xp[1];                              // x(1), consumed in iter 0

  // iter t: computes L1(t) -> h1(t)  AND  L0(t+1) -> h0(t+1); Q=(t+1)&1
#define STEP(Q, TIDX)                                                      \
  {                                                                        \
    float xn = xp[(TIDX)];              /* prefetch x(t+2), stays in flight */ \
    f32x4 e;                                                               \
    e[0] = fmaf(xv, wx[0], bs0[0]);                                        \
    e[1] = fmaf(xv, wx[1], bs0[1]);                                        \
    e[2] = fmaf(xv, wx[2], bs0[2]);                                        \
    e[3] = fmaf(xv, wx[3], bs0[3]);                                        \
    f32x4 u, vv;                                                           \
    __builtin_amdgcn_s_setprio(1);                                         \
    e  = mfma16(W0h, Bh0, e);                                              \
    u  = mfma16(WHh, Bh1, bias1);                                          \
    vv = mfma16(WIh, Bh0, zero4);                                          \
    e  = mfma16(W0l, Bh0, e);                                              \
    u  = mfma16(WHl, Bh1, u);                                              \
    vv = mfma16(WIl, Bh0, vv);                                             \
    __builtin_amdgcn_s_setprio(0);                                         \
    /* L1(t) */                                                            \
    float i1 = sigmoid_f(u[0] + vv[0]), f1 = sigmoid_f(u[1] + vv[1]);      \
    float g1 = tanh_fast(u[2] + vv[2]), o1 = sigmoid_f(u[3] + vv[3]);      \
    c1 = fmaf(f1, c1, i1 * g1);                                            \
    h1v = o1 * tanh_fast(c1);                                              \
    hpl[(Q)][1][wrI] = (_Float16)h1v;                                      \
    /* L0(t+1) */                                                          \
    float i0 = sigmoid_f(e[0]), f0 = sigmoid_f(e[1]);                      \
    float g0 = tanh_fast(e[2]), o0 = sigmoid_f(e[3]);                      \
    c0 = fmaf(f0, c0, i0 * g0);                                            \
    float h0 = o0 * tanh_fast(c0);                                         \
    hpl[(Q)][0][wrI] = (_Float16)h0;                                       \
    lds_barrier();                                                         \
    Bh0 = *(const half8*)&hpl[(Q)][0][rdI];                                \
    Bh1 = *(const half8*)&hpl[(Q)][1][rdI];                                \
    xv = xn;                                                               \
  }

  for (int T0 = 0; T0 < Tn; T0 += 4){
    STEP(1, T0 + 2);
    STEP(0, T0 + 3);
    STEP(1, (T0 + 4 < Tn) ? T0 + 4 : Tn - 1);
    STEP(0, (T0 + 5 < Tn) ? T0 + 5 : Tn - 1);
  }
#undef STEP

  // ---- FC head: out[b0+c] = dot(h1_final[:,c], Wfc) + bfc ----
  __syncthreads();
  float* sc = (float*)&hpl[0][0][0];
  sc[s*17 + col] = h1v;
  __syncthreads();
  if (tid < 16){
    float acc = bfc[0];
    #pragma unroll 8
    for (int k = 0; k < HSZ; ++k) acc = fmaf(sc[k*17 + tid], Wfc[k], acc);
    out[b0 + tid] = acc;
  }
}

extern "C" void kernel_launch(void* const* d_in, const int* in_sizes, int n_in,
                              void* d_out, int out_size, void* d_ws, size_t ws_size,
                              hipStream_t stream) {
  const float* x    = (const float*)d_in[0];
  const float* Wih0 = (const float*)d_in[1];
  const float* Whh0 = (const float*)d_in[2];
  const float* bih0 = (const float*)d_in[3];
  const float* bhh0 = (const float*)d_in[4];
  const float* Wih1 = (const float*)d_in[5];
  const float* Whh1 = (const float*)d_in[6];
  const float* bih1 = (const float*)d_in[7];
  const float* bhh1 = (const float*)d_in[8];
  const float* Wfc  = (const float*)d_in[9];
  const float* bfc  = (const float*)d_in[10];
  float* out = (float*)d_out;

  const int Tn = TLEN;
  const int B  = in_sizes[0] / Tn;     // x is (B, T, 1)

  dim3 block(512);
  dim3 grid(B / 16);
  hipLaunchKernelGGL(lstm2_mfma8, grid, block, 0, stream,
                     x, Wih0, Whh0, bih0, bhh0, Wih1, Whh1, bih1, bhh1,
                     Wfc, bfc, out, Tn);
}

// Round 9
// 419.979 us; speedup vs baseline: 1.3052x; 1.0168x over previous
//
#include <hip/hip_runtime.h>

#define HSZ  32
#define TLEN 1024
#define PS   40   // f16 stride per col in a plane (80 B: 16B-aligned b128 reads)

typedef _Float16 half8 __attribute__((ext_vector_type(8)));
typedef float    f32x4 __attribute__((ext_vector_type(4)));

__device__ __forceinline__ float rcp_f(float x){ return __builtin_amdgcn_rcpf(x); }
__device__ __forceinline__ float exp2_f(float x){ return __builtin_amdgcn_exp2f(x); }
#define LOG2E 1.442695040888963f
#define SCL_S (-1.442695040888963f)   // sigmoid arg prescale: -log2(e)
#define SCL_T ( 2.885390081777927f)   // tanh arg prescale: +2*log2(e)
__device__ __forceinline__ f32x4 mfma16(half8 a, half8 b, f32x4 c){
  return __builtin_amdgcn_mfma_f32_16x16x32_f16(a, b, c, 0, 0, 0);
}

// LDS-only barrier: drain lgkmcnt (ds ops visible) WITHOUT draining vmcnt,
// so the x global prefetch stays in flight across step barriers.
__device__ __forceinline__ void lds_barrier(){
  asm volatile("s_waitcnt lgkmcnt(0)\n\ts_barrier" ::: "memory");
}

// 8 waves = one 16-batch tile; permuted A-row trick: A tile-row r loads physical
// gate row 32*(r&3)+4w+(r>>2), so lane (g,col) D-regs j=0..3 are gates (i,f,g,o)
// of state s=4w+g -- whole quad in-lane, no gate LDS round-trip.
//
// h exchanged as f16-hi only (R8-validated, absmax 2.4e-4 of 8.3e-4 budget);
// weights keep hi+lo split -> 6 MFMA/step in three depth-2 chains.
//
// TRANS REDUCTION (this round):
//  * weights/biases PRESCALED by -log2e (sigmoid rows) / +2log2e (tanh row),
//    so acts need no argument mul: sig = rcp(1+exp2(s)), tanh = 1-2*rcp(1+exp2(s)).
//  * rcp PAIRING (exact to ~2ulp): r=rcp(a*b) gives 1/a=r*b, 1/b=r*a.
//    Pairs: (i,f), (g,o) per layer; tanh(c1)<->tanh(c0) across chains.
//  20 -> 15 trans wave-ops/step (10 exp2 + 5 rcp).
__global__ __launch_bounds__(512, 2) void lstm2_mfma9(
    const float* __restrict__ x,
    const float* __restrict__ Wih0, const float* __restrict__ Whh0,
    const float* __restrict__ bih0, const float* __restrict__ bhh0,
    const float* __restrict__ Wih1, const float* __restrict__ Whh1,
    const float* __restrict__ bih1, const float* __restrict__ bhh1,
    const float* __restrict__ Wfc,  const float* __restrict__ bfc,
    float* __restrict__ out, int Tn)
{
  // [parity][layer][col*PS + k]  (f16 hi plane only)
  __shared__ __align__(16) _Float16 hpl[2][2][16*PS];

  const int tid = threadIdx.x;
  const int w   = tid >> 6;
  const int l   = tid & 63;
  const int col = l & 15;        // batch col == A tile-row index
  const int g   = l >> 4;        // k-group == D row-group
  const int s   = 4*w + g;       // state this lane owns
  const int b0  = blockIdx.x * 16;

  // ---- A fragments: prescaled, hi + lo halves, permuted rows, k = 8g+j ----
  const int prow = 32*(col & 3) + 4*w + (col >> 2);
  const float sA = ((col & 3) == 2) ? SCL_T : SCL_S;   // gate type of this lane's A-rows
  half8 W0h, W0l, WIh, WIl, WHh, WHl;
  {
    const float* p0 = Whh0 + prow*HSZ + 8*g;
    const float* p1 = Wih1 + prow*HSZ + 8*g;
    const float* p2 = Whh1 + prow*HSZ + 8*g;
    #pragma unroll
    for (int j = 0; j < 8; ++j){
      float v0 = p0[j]*sA, v1 = p1[j]*sA, v2 = p2[j]*sA;
      _Float16 a = (_Float16)v0; W0h[j] = a; W0l[j] = (_Float16)(v0 - (float)a);
      _Float16 b = (_Float16)v1; WIh[j] = b; WIl[j] = (_Float16)(v1 - (float)b);
      _Float16 c = (_Float16)v2; WHh[j] = c; WHl[j] = (_Float16)(v2 - (float)c);
    }
  }
  // D reg j = physical gate row 32j + s; per-gate prescale (j=2 is tanh)
  const float scj[4] = {SCL_S, SCL_S, SCL_T, SCL_S};
  float wx[4], bs0[4];
  f32x4 bias1;
  #pragma unroll
  for (int j = 0; j < 4; ++j){
    int r    = 32*j + s;
    wx[j]    = Wih0[r] * scj[j];
    bs0[j]   = (bih0[r] + bhh0[r]) * scj[j];
    bias1[j] = (bih1[r] + bhh1[r]) * scj[j];
  }
  const f32x4 zero4 = {0.f, 0.f, 0.f, 0.f};   // loop-invariant C-seed (C != D)

  const int wrI = col*PS + s;        // f16 index of this lane's h write
  const int rdI = col*PS + 8*g;      // f16 index of b128 read (16B-aligned)

  for (int i = tid; i < 2*2*16*PS; i += 512) (&hpl[0][0][0])[i] = (_Float16)0.0f;

  const float* xp = x + (size_t)(b0 + col) * Tn;
  float c0, c1 = 0.f, h1v = 0.f;

  // ---- prologue: L0(0) has h0(-1)=0 -> no MFMA; h1(-1)=0 stays in [0][1] ----
  {
    float x0 = xp[0];
    float e0 = fmaf(x0, wx[0], bs0[0]);   // prescaled sigmoid arg
    float e2 = fmaf(x0, wx[2], bs0[2]);   // prescaled tanh arg
    float e3 = fmaf(x0, wx[3], bs0[3]);
    float i0 = rcp_f(1.f + exp2_f(e0));
    float g0 = fmaf(-2.f, rcp_f(1.f + exp2_f(e2)), 1.f);
    float o0 = rcp_f(1.f + exp2_f(e3));
    c0 = i0 * g0;                         // f0 * c0(-1) = 0
    float th = fmaf(-2.f, rcp_f(1.f + exp2_f(SCL_T * c0)), 1.f);
    float h0 = o0 * th;
    __syncthreads();                      // zero-init visible before overwrite/read
    hpl[0][0][wrI] = (_Float16)h0;
  }
  __syncthreads();
  half8 Bh0 = *(const half8*)&hpl[0][0][rdI];   // h0(0)
  half8 Bh1 = *(const half8*)&hpl[0][1][rdI];   // h1(-1) = 0
  float xv = xp[1];                              // x(1), consumed in iter 0

  // iter t: computes L1(t) -> h1(t)  AND  L0(t+1) -> h0(t+1); Q=(t+1)&1
#define STEP(Q, TIDX)                                                      \
  {                                                                        \
    float xn = xp[(TIDX)];              /* prefetch x(t+2), stays in flight */ \
    f32x4 e;                                                               \
    e[0] = fmaf(xv, wx[0], bs0[0]);                                        \
    e[1] = fmaf(xv, wx[1], bs0[1]);                                        \
    e[2] = fmaf(xv, wx[2], bs0[2]);                                        \
    e[3] = fmaf(xv, wx[3], bs0[3]);                                        \
    f32x4 u, vv;                                                           \
    __builtin_amdgcn_s_setprio(1);                                         \
    e  = mfma16(W0h, Bh0, e);                                              \
    u  = mfma16(WHh, Bh1, bias1);                                          \
    vv = mfma16(WIh, Bh0, zero4);                                          \
    e  = mfma16(W0l, Bh0, e);                                              \
    u  = mfma16(WHl, Bh1, u);                                              \
    vv = mfma16(WIl, Bh0, vv);                                             \
    __builtin_amdgcn_s_setprio(0);                                         \
    /* ---- L1(t) acts (prescaled args; paired rcps) ---- */               \
    float Zi = exp2_f(u[0] + vv[0]), Zf = exp2_f(u[1] + vv[1]);            \
    float Zg = exp2_f(u[2] + vv[2]), Zo = exp2_f(u[3] + vv[3]);            \
    float di = 1.f + Zi, df = 1.f + Zf, dg = 1.f + Zg, dq = 1.f + Zo;      \
    float ra = rcp_f(di * df);                                             \
    float i1 = ra * df, f1 = ra * di;                                      \
    float rb = rcp_f(dg * dq);                                             \
    float g1 = fmaf(-2.f, rb * dq, 1.f);                                   \
    float o1 = rb * dg;                                                    \
    c1 = fmaf(f1, c1, i1 * g1);                                            \
    float Zc1 = exp2_f(SCL_T * c1);                                        \
    float dc1 = 1.f + Zc1;                                                 \
    /* ---- L0(t+1) acts ---- */                                           \
    float Xi = exp2_f(e[0]), Xf = exp2_f(e[1]);                            \
    float Xg = exp2_f(e[2]), Xo = exp2_f(e[3]);                            \
    float ei = 1.f + Xi, ef = 1.f + Xf, eg = 1.f + Xg, eq = 1.f + Xo;      \
    float rc2 = rcp_f(ei * ef);                                            \
    float i0 = rc2 * ef, f0 = rc2 * ei;                                    \
    float rd2 = rcp_f(eg * eq);                                            \
    float g0 = fmaf(-2.f, rd2 * eq, 1.f);                                  \
    float o0 = rd2 * eg;                                                   \
    c0 = fmaf(f0, c0, i0 * g0);                                            \
    float Zc0 = exp2_f(SCL_T * c0);                                        \
    float dc0 = 1.f + Zc0;                                                 \
    /* ---- cross-layer paired tanh(c) ---- */                             \
    float re = rcp_f(dc1 * dc0);                                           \
    float t1 = re * dc0, t0 = re * dc1;                                    \
    float q1 = t1 * o1; h1v = fmaf(-2.f, q1, o1);                          \
    float q0 = t0 * o0; float h0 = fmaf(-2.f, q0, o0);                     \
    hpl[(Q)][1][wrI] = (_Float16)h1v;                                      \
    hpl[(Q)][0][wrI] = (_Float16)h0;                                       \
    lds_barrier();                                                         \
    Bh0 = *(const half8*)&hpl[(Q)][0][rdI];                                \
    Bh1 = *(const half8*)&hpl[(Q)][1][rdI];                                \
    xv = xn;                                                               \
  }

  for (int T0 = 0; T0 < Tn; T0 += 4){
    STEP(1, T0 + 2);
    STEP(0, T0 + 3);
    STEP(1, (T0 + 4 < Tn) ? T0 + 4 : Tn - 1);
    STEP(0, (T0 + 5 < Tn) ? T0 + 5 : Tn - 1);
  }
#undef STEP

  // ---- FC head: out[b0+c] = dot(h1_final[:,c], Wfc) + bfc ----
  __syncthreads();
  float* sc = (float*)&hpl[0][0][0];
  sc[s*17 + col] = h1v;
  __syncthreads();
  if (tid < 16){
    float acc = bfc[0];
    #pragma unroll 8
    for (int k = 0; k < HSZ; ++k) acc = fmaf(sc[k*17 + tid], Wfc[k], acc);
    out[b0 + tid] = acc;
  }
}

extern "C" void kernel_launch(void* const* d_in, const int* in_sizes, int n_in,
                              void* d_out, int out_size, void* d_ws, size_t ws_size,
                              hipStream_t stream) {
  const float* x    = (const float*)d_in[0];
  const float* Wih0 = (const float*)d_in[1];
  const float* Whh0 = (const float*)d_in[2];
  const float* bih0 = (const float*)d_in[3];
  const float* bhh0 = (const float*)d_in[4];
  const float* Wih1 = (const float*)d_in[5];
  const float* Whh1 = (const float*)d_in[6];
  const float* bih1 = (const float*)d_in[7];
  const float* bhh1 = (const float*)d_in[8];
  const float* Wfc  = (const float*)d_in[9];
  const float* bfc  = (const float*)d_in[10];
  float* out = (float*)d_out;

  const int Tn = TLEN;
  const int B  = in_sizes[0] / Tn;     // x is (B, T, 1)

  dim3 block(512);
  dim3 grid(B / 16);
  hipLaunchKernelGGL(lstm2_mfma9, grid, block, 0, stream,
                     x, Wih0, Whh0, bih0, bhh0, Wih1, Whh1, bih1, bhh1,
                     Wfc, bfc, out, Tn);
}

// Round 10
// 411.784 us; speedup vs baseline: 1.3312x; 1.0199x over previous
//
#include <hip/hip_runtime.h>

#define HSZ  32
#define TLEN 1024
#define PS   40   // f16 stride per col in a plane (80 B: 16B-aligned b128 reads)

typedef _Float16 half8 __attribute__((ext_vector_type(8)));
typedef float    f32x4 __attribute__((ext_vector_type(4)));

__device__ __forceinline__ float rcp_f(float x){ return __builtin_amdgcn_rcpf(x); }
__device__ __forceinline__ float exp2_f(float x){ return __builtin_amdgcn_exp2f(x); }
#define SCL_S (-1.442695040888963f)   // sigmoid arg prescale: -log2(e)
#define SCL_T ( 2.885390081777927f)   // tanh arg prescale: +2*log2(e)

__device__ __forceinline__ f32x4 mfma16(half8 a, half8 b, f32x4 c){
  return __builtin_amdgcn_mfma_f32_16x16x32_f16(a, b, c, 0, 0, 0);
}
// LDS-only barrier: drain lgkmcnt without draining vmcnt (x prefetch stays in flight).
__device__ __forceinline__ void lds_barrier(){
  asm volatile("s_waitcnt lgkmcnt(0)\n\ts_barrier" ::: "memory");
}

// gate quad from prescaled args; paired rcps; updates CV in place.
#define ACT4(A0,A1,A2,A3, CV, IV, FV, GV, OV)                  \
  { float Zi_ = exp2_f(A0), Zf_ = exp2_f(A1);                  \
    float Zg_ = exp2_f(A2), Zo_ = exp2_f(A3);                  \
    float di_ = 1.f+Zi_, df_ = 1.f+Zf_;                        \
    float dg_ = 1.f+Zg_, dq_ = 1.f+Zo_;                        \
    float r1_ = rcp_f(di_*df_); IV = r1_*df_; FV = r1_*di_;    \
    float r2_ = rcp_f(dg_*dq_);                                \
    GV = fmaf(-2.f, r2_*dq_, 1.f); OV = r2_*dg_;               \
    CV = fmaf(FV, CV, IV*GV); }

// paired tanh(c) for the wave's two states (same layer): one rcp.
#define TANHPAIR(CA, CB, OA, OB, HA, HB)                       \
  { float ZA_ = exp2_f(SCL_T*(CA)), ZB_ = exp2_f(SCL_T*(CB));  \
    float dA_ = 1.f+ZA_, dB_ = 1.f+ZB_;                        \
    float re_ = rcp_f(dA_*dB_);                                \
    float qA_ = re_*dB_*(OA), qB_ = re_*dA_*(OB);              \
    HA = fmaf(-2.f, qA_, OA); HB = fmaf(-2.f, qB_, OB); }

// PRODUCER/CONSUMER WAVE SPECIALIZATION, 16-batch tile per block (8 waves):
//   waves 0-3 (L0): own layer-0 states 8wl..8wl+7 (two permuted 16-row D-tiles,
//     4 MFMA/step). L0's recurrence is self-contained: it runs one step AHEAD,
//     publishing h0(t+1) while L1 waves compute h1(t).
//   waves 4-7 (L1): own layer-1 states 8wl..8wl+7 (8 MFMA/step: Whh1*h1 + Wih1*h0).
// Permuted A-row trick per tile (rows 32*(r&3)+S+(r>>2)): lane (g,col) D-regs
// j=0..3 = gates (i,f,g,o) of state S+g -- whole quad in-lane, no gate LDS.
// h exchanged as f16-hi only; weights keep hi+lo split (R8/R9-validated).
// ONE lgkm-only barrier per step; parity double-buffered planes; critical path
// per barrier interval = max(L0 chain, L1 chain) instead of their sum.
__global__ __launch_bounds__(512, 2) void lstm2_pc(
    const float* __restrict__ x,
    const float* __restrict__ Wih0, const float* __restrict__ Whh0,
    const float* __restrict__ bih0, const float* __restrict__ bhh0,
    const float* __restrict__ Wih1, const float* __restrict__ Whh1,
    const float* __restrict__ bih1, const float* __restrict__ bhh1,
    const float* __restrict__ Wfc,  const float* __restrict__ bfc,
    float* __restrict__ out, int Tn)
{
  __shared__ __align__(16) _Float16 hpl[2][2][16*PS];  // [parity][layer][col*PS+k]

  const int tid = threadIdx.x;
  const int w   = tid >> 6;
  const int l   = tid & 63;
  const int col = l & 15;        // batch col == A tile-row index
  const int g   = l >> 4;        // k-group == D row-group
  const int wl  = w & 3;         // group-local wave id: states 8wl..8wl+7
  const int b0  = blockIdx.x * 16;
  const bool isL0 = (w < 4);

  const int rdI = col*PS + 8*g;        // b128 read (16B-aligned)
  const int wrA = col*PS + 8*wl + g;   // state 8wl+g
  const int wrB = wrA + 4;             // state 8wl+4+g
  const float sA = ((col & 3) == 2) ? SCL_T : SCL_S;
  const float scj[4] = {SCL_S, SCL_S, SCL_T, SCL_S};
  const f32x4 zero4 = {0.f, 0.f, 0.f, 0.f};

  for (int i = tid; i < 2*2*16*PS; i += 512) (&hpl[0][0][0])[i] = (_Float16)0.0f;

  // L0 per-state constants (loaded by all; dead in L1 branch)
  float wxA[4], wxB[4], bsA[4], bsB[4];
  #pragma unroll
  for (int j = 0; j < 4; ++j){
    int rA = 32*j + 8*wl + g, rB = rA + 4;
    wxA[j] = Wih0[rA] * scj[j];
    wxB[j] = Wih0[rB] * scj[j];
    bsA[j] = (bih0[rA] + bhh0[rA]) * scj[j];
    bsB[j] = (bih1 == bih1 ? (bih0[rB] + bhh0[rB]) : 0.f) * scj[j];
  }
  const float* xp = x + (size_t)(b0 + col) * Tn;

  __syncthreads();   // [A] zero-init visible

  // ---- prologue: L0 computes h0(0) (no MFMA, h0(-1)=0); h1(-1)=0 already ----
  if (isL0){
    float x0 = xp[0];
    float c0A = 0.f, c0B = 0.f, iA,fA,gA,oA, iB,fB,gB,oB, h0A, h0B;
    ACT4(fmaf(x0,wxA[0],bsA[0]), fmaf(x0,wxA[1],bsA[1]),
         fmaf(x0,wxA[2],bsA[2]), fmaf(x0,wxA[3],bsA[3]), c0A, iA,fA,gA,oA);
    ACT4(fmaf(x0,wxB[0],bsB[0]), fmaf(x0,wxB[1],bsB[1]),
         fmaf(x0,wxB[2],bsB[2]), fmaf(x0,wxB[3],bsB[3]), c0B, iB,fB,gB,oB);
    TANHPAIR(c0A, c0B, oA, oB, h0A, h0B);
    hpl[0][0][wrA] = (_Float16)h0A;
    hpl[0][0][wrB] = (_Float16)h0B;
    // carry c into the loop via registers below
    wxA[0] = wxA[0]; // no-op
    // stash carried state in outer scope through branch-local vars (re-declared in loop)
    // (c0A/c0B handed off via the branch body below)
    // -- we re-enter the L0 branch right after [B] with these values --
    // store them in the bs arrays? no: keep in branch scope by fusing below.
    // (handled by structuring the branch to include both prologue and loop)
    // This block intentionally only writes LDS; c values recomputed there.
    ;
  }
  __syncthreads();   // [B] h0(0) visible

  float h1Av = 0.f, h1Bv = 0.f;    // L1 finals for FC head

  if (isL0){
    // ================= LAYER-0 PRODUCER =================
    const int prowA = 32*(col & 3) + 8*wl + (col >> 2);
    half8 WhA, WlA, WhB, WlB;
    {
      const float* pA = Whh0 + prowA*HSZ + 8*g;
      const float* pB = pA + 4*HSZ;              // prowB = prowA + 4
      #pragma unroll
      for (int j = 0; j < 8; ++j){
        float vA = pA[j]*sA, vB = pB[j]*sA;
        _Float16 a = (_Float16)vA; WhA[j] = a; WlA[j] = (_Float16)(vA - (float)a);
        _Float16 b = (_Float16)vB; WhB[j] = b; WlB[j] = (_Float16)(vB - (float)b);
      }
    }
    // recompute prologue c (cheap, keeps scoping simple; matches written h0(0))
    float c0A = 0.f, c0B = 0.f;
    {
      float x0 = xp[0];
      float iA,fA,gA,oA, iB,fB,gB,oB;
      ACT4(fmaf(x0,wxA[0],bsA[0]), fmaf(x0,wxA[1],bsA[1]),
           fmaf(x0,wxA[2],bsA[2]), fmaf(x0,wxA[3],bsA[3]), c0A, iA,fA,gA,oA);
      ACT4(fmaf(x0,wxB[0],bsB[0]), fmaf(x0,wxB[1],bsB[1]),
           fmaf(x0,wxB[2],bsB[2]), fmaf(x0,wxB[3],bsB[3]), c0B, iB,fB,gB,oB);
    }
    half8 Bh0 = *(const half8*)&hpl[0][0][rdI];   // h0(0)
    float xv = xp[1];

#define L0STEP(Q, XNI)                                                     \
    {                                                                      \
      float xn = xp[(XNI)];                                                \
      f32x4 eA, eB;                                                        \
      eA[0]=fmaf(xv,wxA[0],bsA[0]); eA[1]=fmaf(xv,wxA[1],bsA[1]);          \
      eA[2]=fmaf(xv,wxA[2],bsA[2]); eA[3]=fmaf(xv,wxA[3],bsA[3]);          \
      eB[0]=fmaf(xv,wxB[0],bsB[0]); eB[1]=fmaf(xv,wxB[1],bsB[1]);          \
      eB[2]=fmaf(xv,wxB[2],bsB[2]); eB[3]=fmaf(xv,wxB[3],bsB[3]);          \
      __builtin_amdgcn_s_setprio(1);                                       \
      eA = mfma16(WhA, Bh0, eA);  eB = mfma16(WhB, Bh0, eB);               \
      eA = mfma16(WlA, Bh0, eA);  eB = mfma16(WlB, Bh0, eB);               \
      __builtin_amdgcn_s_setprio(0);                                       \
      float iA,fA,gA,oA, iB,fB,gB,oB, h0A, h0B;                            \
      ACT4(eA[0],eA[1],eA[2],eA[3], c0A, iA,fA,gA,oA);                     \
      ACT4(eB[0],eB[1],eB[2],eB[3], c0B, iB,fB,gB,oB);                     \
      TANHPAIR(c0A, c0B, oA, oB, h0A, h0B);                                \
      hpl[(Q)][0][wrA] = (_Float16)h0A;                                    \
      hpl[(Q)][0][wrB] = (_Float16)h0B;                                    \
      lds_barrier();                                                       \
      Bh0 = *(const half8*)&hpl[(Q)][0][rdI];                              \
      xv = xn;                                                             \
    }

    for (int T0 = 0; T0 < Tn; T0 += 2){
      L0STEP(1, (T0+2 < Tn) ? T0+2 : Tn-1);
      L0STEP(0, (T0+3 < Tn) ? T0+3 : Tn-1);
    }
#undef L0STEP
  } else {
    // ================= LAYER-1 CONSUMER =================
    const int prowA = 32*(col & 3) + 8*wl + (col >> 2);
    half8 WIhA, WIlA, WIhB, WIlB, WHhA, WHlA, WHhB, WHlB;
    {
      const float* iA_ = Wih1 + prowA*HSZ + 8*g;
      const float* iB_ = iA_ + 4*HSZ;
      const float* hA_ = Whh1 + prowA*HSZ + 8*g;
      const float* hB_ = hA_ + 4*HSZ;
      #pragma unroll
      for (int j = 0; j < 8; ++j){
        float v0 = iA_[j]*sA, v1 = iB_[j]*sA, v2 = hA_[j]*sA, v3 = hB_[j]*sA;
        _Float16 a = (_Float16)v0; WIhA[j] = a; WIlA[j] = (_Float16)(v0 - (float)a);
        _Float16 b = (_Float16)v1; WIhB[j] = b; WIlB[j] = (_Float16)(v1 - (float)b);
        _Float16 c = (_Float16)v2; WHhA[j] = c; WHlA[j] = (_Float16)(v2 - (float)c);
        _Float16 d = (_Float16)v3; WHhB[j] = d; WHlB[j] = (_Float16)(v3 - (float)d);
      }
    }
    f32x4 bias1A, bias1B;
    #pragma unroll
    for (int j = 0; j < 4; ++j){
      int rA = 32*j + 8*wl + g, rB = rA + 4;
      bias1A[j] = (bih1[rA] + bhh1[rA]) * scj[j];
      bias1B[j] = (bih1[rB] + bhh1[rB]) * scj[j];
    }
    float c1A = 0.f, c1B = 0.f;
    half8 Bh0 = *(const half8*)&hpl[0][0][rdI];   // h0(0)
    half8 Bh1 = *(const half8*)&hpl[0][1][rdI];   // h1(-1) = 0

#define L1STEP(Q)                                                          \
    {                                                                      \
      f32x4 uA, uB, vvA, vvB;                                              \
      __builtin_amdgcn_s_setprio(1);                                       \
      uA  = mfma16(WHhA, Bh1, bias1A);  uB  = mfma16(WHhB, Bh1, bias1B);   \
      vvA = mfma16(WIhA, Bh0, zero4);   vvB = mfma16(WIhB, Bh0, zero4);    \
      uA  = mfma16(WHlA, Bh1, uA);      uB  = mfma16(WHlB, Bh1, uB);       \
      vvA = mfma16(WIlA, Bh0, vvA);     vvB = mfma16(WIlB, Bh0, vvB);      \
      __builtin_amdgcn_s_setprio(0);                                       \
      f32x4 aA = uA + vvA, aB = uB + vvB;                                  \
      float iA,fA,gA,oA, iB,fB,gB,oB;                                      \
      ACT4(aA[0],aA[1],aA[2],aA[3], c1A, iA,fA,gA,oA);                     \
      ACT4(aB[0],aB[1],aB[2],aB[3], c1B, iB,fB,gB,oB);                     \
      TANHPAIR(c1A, c1B, oA, oB, h1Av, h1Bv);                              \
      hpl[(Q)][1][wrA] = (_Float16)h1Av;                                   \
      hpl[(Q)][1][wrB] = (_Float16)h1Bv;                                   \
      lds_barrier();                                                       \
      Bh0 = *(const half8*)&hpl[(Q)][0][rdI];                              \
      Bh1 = *(const half8*)&hpl[(Q)][1][rdI];                              \
    }

    for (int T0 = 0; T0 < Tn; T0 += 2){
      L1STEP(1);
      L1STEP(0);
    }
#undef L1STEP
  }

  // ---- FC head: out[b0+c] = dot(h1_final[:,c], Wfc) + bfc ----
  __syncthreads();   // [C] loops done everywhere
  float* sc = (float*)&hpl[0][0][0];
  if (w >= 4){
    sc[(8*wl + g)*17 + col]     = h1Av;
    sc[(8*wl + 4 + g)*17 + col] = h1Bv;
  }
  __syncthreads();   // [D]
  if (tid < 16){
    float acc = bfc[0];
    #pragma unroll 8
    for (int k = 0; k < HSZ; ++k) acc = fmaf(sc[k*17 + tid], Wfc[k], acc);
    out[b0 + tid] = acc;
  }
}

extern "C" void kernel_launch(void* const* d_in, const int* in_sizes, int n_in,
                              void* d_out, int out_size, void* d_ws, size_t ws_size,
                              hipStream_t stream) {
  const float* x    = (const float*)d_in[0];
  const float* Wih0 = (const float*)d_in[1];
  const float* Whh0 = (const float*)d_in[2];
  const float* bih0 = (const float*)d_in[3];
  const float* bhh0 = (const float*)d_in[4];
  const float* Wih1 = (const float*)d_in[5];
  const float* Whh1 = (const float*)d_in[6];
  const float* bih1 = (const float*)d_in[7];
  const float* bhh1 = (const float*)d_in[8];
  const float* Wfc  = (const float*)d_in[9];
  const float* bfc  = (const float*)d_in[10];
  float* out = (float*)d_out;

  const int Tn = TLEN;
  const int B  = in_sizes[0] / Tn;     // x is (B, T, 1)

  dim3 block(512);
  dim3 grid(B / 16);
  hipLaunchKernelGGL(lstm2_pc, grid, block, 0, stream,
                     x, Wih0, Whh0, bih0, bhh0, Wih1, Whh1, bih1, bhh1,
                     Wfc, bfc, out, Tn);
}

// Round 11
// 408.586 us; speedup vs baseline: 1.3416x; 1.0078x over previous
//
#include <hip/hip_runtime.h>

#define HSZ  32
#define TLEN 1024
#define PS   40   // f16 stride per col in a plane (80 B: 16B-aligned b128 reads)

typedef _Float16 half8 __attribute__((ext_vector_type(8)));
typedef float    f32x4 __attribute__((ext_vector_type(4)));

__device__ __forceinline__ float rcp_f(float x){ return __builtin_amdgcn_rcpf(x); }
__device__ __forceinline__ float exp2_f(float x){ return __builtin_amdgcn_exp2f(x); }
#define SCL_S (-1.442695040888963f)   // sigmoid arg prescale: -log2(e)
#define SCL_T ( 2.885390081777927f)   // tanh arg prescale: +2*log2(e)

__device__ __forceinline__ f32x4 mfma16(half8 a, half8 b, f32x4 c){
  return __builtin_amdgcn_mfma_f32_16x16x32_f16(a, b, c, 0, 0, 0);
}
// LDS-only barrier: drain lgkmcnt without draining vmcnt (x prefetch stays in flight).
__device__ __forceinline__ void lds_barrier(){
  asm volatile("s_waitcnt lgkmcnt(0)\n\ts_barrier" ::: "memory");
}

// gate quad from prescaled args; paired rcps; updates CV in place.
#define ACT4(A0,A1,A2,A3, CV, IV, FV, GV, OV)                  \
  { float Zi_ = exp2_f(A0), Zf_ = exp2_f(A1);                  \
    float Zg_ = exp2_f(A2), Zo_ = exp2_f(A3);                  \
    float di_ = 1.f+Zi_, df_ = 1.f+Zf_;                        \
    float dg_ = 1.f+Zg_, dq_ = 1.f+Zo_;                        \
    float r1_ = rcp_f(di_*df_); IV = r1_*df_; FV = r1_*di_;    \
    float r2_ = rcp_f(dg_*dq_);                                \
    GV = fmaf(-2.f, r2_*dq_, 1.f); OV = r2_*dg_;               \
    CV = fmaf(FV, CV, IV*GV); }

// h = o * tanh(c), prescaled: tanh = 1 - 2*rcp(1+exp2(SCL_T*c))
#define HOUT(CV, OV, HV)                                       \
  { float Zc_ = exp2_f(SCL_T*(CV));                            \
    float rc_ = rcp_f(1.f + Zc_);                              \
    HV = fmaf(-2.f, rc_*(OV), OV); }

// 16 WAVES PER 16-BATCH TILE (4 waves/SIMD -- convoy breaker):
//   waves 0-7  (L0): one permuted D-tile each = 4 states, 2 MFMA/step.
//   waves 8-15 (L1): one D-tile each = 4 states, 4 MFMA/step (Whh1*h1 + Wih1*h0).
// Same total issue per SIMD as the 8-wave version, but 4 resident waves per
// SIMD fill each other's post-barrier ds_read/transcendental latency shadows,
// and per-wave dependency chains halve (one gate quad per lane).
// Permuted A-row trick: tile tau rows = 32*(r&3)+4*tau+(r>>2), so lane (g,col)
// D-regs j=0..3 are gates (i,f,g,o) of state 4*tau+g -- quad in-lane.
// h exchanged as f16-hi only; weights keep hi+lo split (R8/R9-validated).
// ONE lgkm-only barrier per step; parity double-buffered planes.
__global__ __launch_bounds__(1024, 4) void lstm2_w16(
    const float* __restrict__ x,
    const float* __restrict__ Wih0, const float* __restrict__ Whh0,
    const float* __restrict__ bih0, const float* __restrict__ bhh0,
    const float* __restrict__ Wih1, const float* __restrict__ Whh1,
    const float* __restrict__ bih1, const float* __restrict__ bhh1,
    const float* __restrict__ Wfc,  const float* __restrict__ bfc,
    float* __restrict__ out, int Tn)
{
  __shared__ __align__(16) _Float16 hpl[2][2][16*PS];  // [parity][layer][col*PS+k]

  const int tid = threadIdx.x;
  const int w   = tid >> 6;
  const int l   = tid & 63;
  const int col = l & 15;        // batch col == A tile-row index
  const int g   = l >> 4;        // k-group == D row-group
  const int b0  = blockIdx.x * 16;
  const bool isL0 = (w < 8);
  const int wl  = isL0 ? w : (w - 8);   // tile index 0..7
  const int st  = 4*wl + g;             // state this lane owns

  const int rdI = col*PS + 8*g;         // b128 read (16B-aligned)
  const int wrI = col*PS + st;          // this lane's h write
  const float sA = ((col & 3) == 2) ? SCL_T : SCL_S;
  const float scj[4] = {SCL_S, SCL_S, SCL_T, SCL_S};
  const f32x4 zero4 = {0.f, 0.f, 0.f, 0.f};
  const int prow = 32*(col & 3) + 4*wl + (col >> 2);

  for (int i = tid; i < 2*2*16*PS; i += 1024) (&hpl[0][0][0])[i] = (_Float16)0.0f;

  // ---- per-role weight/bias loads (divergent, no barrier inside) ----
  half8 WAh, WAl, WBh, WBl;        // L0: Whh0 hi/lo | L1: Whh1 hi/lo
  f32x4 bias1;                     // L1 only
  float wx[4], bs0[4];             // L0 only
  half8 WIh, WIl;                  // L1 only: Wih1 hi/lo
  const float* xp = x + (size_t)(b0 + col) * Tn;

  if (isL0){
    const float* p0 = Whh0 + prow*HSZ + 8*g;
    #pragma unroll
    for (int j = 0; j < 8; ++j){
      float v0 = p0[j]*sA;
      _Float16 a = (_Float16)v0; WAh[j] = a; WAl[j] = (_Float16)(v0 - (float)a);
    }
    #pragma unroll
    for (int j = 0; j < 4; ++j){
      int r  = 32*j + st;
      wx[j]  = Wih0[r] * scj[j];
      bs0[j] = (bih0[r] + bhh0[r]) * scj[j];
    }
  } else {
    const float* pH = Whh1 + prow*HSZ + 8*g;
    const float* pI = Wih1 + prow*HSZ + 8*g;
    #pragma unroll
    for (int j = 0; j < 8; ++j){
      float v2 = pH[j]*sA, v1 = pI[j]*sA;
      _Float16 c = (_Float16)v2; WAh[j] = c; WAl[j] = (_Float16)(v2 - (float)c);
      _Float16 b = (_Float16)v1; WIh[j] = b; WIl[j] = (_Float16)(v1 - (float)b);
    }
    #pragma unroll
    for (int j = 0; j < 4; ++j){
      int r = 32*j + st;
      bias1[j] = (bih1[r] + bhh1[r]) * scj[j];
    }
  }
  (void)WBh; (void)WBl;

  float cSt = 0.f, hFin = 0.f;     // recurrent cell state / last h (per role)

  __syncthreads();   // [A] zero-init visible

  // ---- prologue: L0 computes h0(0) (no MFMA, h0(-1)=0); h1(-1)=0 already ----
  if (isL0){
    float x0 = xp[0];
    float iv, fv, gv, ov;
    ACT4(fmaf(x0,wx[0],bs0[0]), fmaf(x0,wx[1],bs0[1]),
         fmaf(x0,wx[2],bs0[2]), fmaf(x0,wx[3],bs0[3]), cSt, iv,fv,gv,ov);
    float h0;
    HOUT(cSt, ov, h0);
    hpl[0][0][wrI] = (_Float16)h0;
  }
  __syncthreads();   // [B] h0(0) visible

  if (isL0){
    // ================= LAYER-0 PRODUCER (1 tile, 2 MFMA/step) =================
    half8 Bh0 = *(const half8*)&hpl[0][0][rdI];   // h0(0)
    float xv = xp[1];

#define L0STEP(Q, XNI)                                                     \
    {                                                                      \
      float xn = xp[(XNI)];                                                \
      f32x4 e;                                                             \
      e[0]=fmaf(xv,wx[0],bs0[0]); e[1]=fmaf(xv,wx[1],bs0[1]);              \
      e[2]=fmaf(xv,wx[2],bs0[2]); e[3]=fmaf(xv,wx[3],bs0[3]);              \
      __builtin_amdgcn_s_setprio(1);                                       \
      e = mfma16(WAh, Bh0, e);                                             \
      e = mfma16(WAl, Bh0, e);                                             \
      __builtin_amdgcn_s_setprio(0);                                       \
      float iv, fv, gv, ov, h0;                                            \
      ACT4(e[0],e[1],e[2],e[3], cSt, iv,fv,gv,ov);                         \
      HOUT(cSt, ov, h0);                                                   \
      hpl[(Q)][0][wrI] = (_Float16)h0;                                     \
      lds_barrier();                                                       \
      Bh0 = *(const half8*)&hpl[(Q)][0][rdI];                              \
      xv = xn;                                                             \
    }

    for (int T0 = 0; T0 < Tn; T0 += 2){
      L0STEP(1, (T0+2 < Tn) ? T0+2 : Tn-1);
      L0STEP(0, (T0+3 < Tn) ? T0+3 : Tn-1);
    }
#undef L0STEP
  } else {
    // ================= LAYER-1 CONSUMER (1 tile, 4 MFMA/step) =================
    half8 Bh0 = *(const half8*)&hpl[0][0][rdI];   // h0(0)
    half8 Bh1 = *(const half8*)&hpl[0][1][rdI];   // h1(-1) = 0

#define L1STEP(Q)                                                          \
    {                                                                      \
      f32x4 u, vv;                                                         \
      __builtin_amdgcn_s_setprio(1);                                       \
      u  = mfma16(WAh, Bh1, bias1);                                        \
      vv = mfma16(WIh, Bh0, zero4);                                        \
      u  = mfma16(WAl, Bh1, u);                                            \
      vv = mfma16(WIl, Bh0, vv);                                           \
      __builtin_amdgcn_s_setprio(0);                                       \
      f32x4 a = u + vv;                                                    \
      float iv, fv, gv, ov;                                                \
      ACT4(a[0],a[1],a[2],a[3], cSt, iv,fv,gv,ov);                         \
      HOUT(cSt, ov, hFin);                                                 \
      hpl[(Q)][1][wrI] = (_Float16)hFin;                                   \
      lds_barrier();                                                       \
      Bh0 = *(const half8*)&hpl[(Q)][0][rdI];                              \
      Bh1 = *(const half8*)&hpl[(Q)][1][rdI];                              \
    }

    for (int T0 = 0; T0 < Tn; T0 += 2){
      L1STEP(1);
      L1STEP(0);
    }
#undef L1STEP
  }

  // ---- FC head: out[b0+c] = dot(h1_final[:,c], Wfc) + bfc ----
  __syncthreads();   // [C] loops done everywhere
  float* sc = (float*)&hpl[0][0][0];
  if (!isL0){
    sc[st*17 + col] = hFin;
  }
  __syncthreads();   // [D]
  if (tid < 16){
    float acc = bfc[0];
    #pragma unroll 8
    for (int k = 0; k < HSZ; ++k) acc = fmaf(sc[k*17 + tid], Wfc[k], acc);
    out[b0 + tid] = acc;
  }
}

extern "C" void kernel_launch(void* const* d_in, const int* in_sizes, int n_in,
                              void* d_out, int out_size, void* d_ws, size_t ws_size,
                              hipStream_t stream) {
  const float* x    = (const float*)d_in[0];
  const float* Wih0 = (const float*)d_in[1];
  const float* Whh0 = (const float*)d_in[2];
  const float* bih0 = (const float*)d_in[3];
  const float* bhh0 = (const float*)d_in[4];
  const float* Wih1 = (const float*)d_in[5];
  const float* Whh1 = (const float*)d_in[6];
  const float* bih1 = (const float*)d_in[7];
  const float* bhh1 = (const float*)d_in[8];
  const float* Wfc  = (const float*)d_in[9];
  const float* bfc  = (const float*)d_in[10];
  float* out = (float*)d_out;

  const int Tn = TLEN;
  const int B  = in_sizes[0] / Tn;     // x is (B, T, 1)

  dim3 block(1024);
  dim3 grid(B / 16);
  hipLaunchKernelGGL(lstm2_w16, grid, block, 0, stream,
                     x, Wih0, Whh0, bih0, bhh0, Wih1, Whh1, bih1, bhh1,
                     Wfc, bfc, out, Tn);
}